// Round 14
// baseline (416.397 us; speedup 1.0000x reference)
//
#include <hip/hip_runtime.h>

#define B_ 32
#define S_ 512
#define D_ 512
#define H_ 8
#define DK_ 64
#define FF_ 2048

typedef float f32x4 __attribute__((ext_vector_type(4)));
typedef __bf16 bf16x8 __attribute__((ext_vector_type(8)));
typedef __bf16 bf16x4 __attribute__((ext_vector_type(4)));

// ---- async global->LDS, 16B per lane (dest must be wave-uniform base + lane*16) ----
__device__ __forceinline__ void gld_lds16(const void* gptr, void* lptr) {
    auto g = (__attribute__((address_space(1))) void*)(unsigned long long)gptr;
    auto l = (__attribute__((address_space(3))) void*)(unsigned)(unsigned long long)lptr;
    __builtin_amdgcn_global_load_lds(g, l, 16, 0, 0);
}

// ---- shared 32x32 transpose tile body: fp32 [R][C] -> bf16 [C][R] ----
__device__ __forceinline__ void ttile(
    const float* __restrict__ in, __bf16* __restrict__ out,
    int R, int C, int bx, int by, int t)
{
    __shared__ float tile[32][33];
    const int tc = bx * 32, tr = by * 32;
    const int lx = t & 31, ly = t >> 5;
    #pragma unroll
    for (int yy = ly; yy < 32; yy += 8)
        tile[yy][lx] = in[(long)(tr + yy) * C + tc + lx];
    __syncthreads();
    #pragma unroll
    for (int yy = ly; yy < 32; yy += 8)
        out[(long)(tc + yy) * R + tr + lx] = (__bf16)tile[lx][yy];
}

// ---- weight transposes + x/y prep fused into one flat-grid dispatch ----
__global__ __launch_bounds__(256) void pre_all(
    const float* __restrict__ Wk, const float* __restrict__ Wv,
    const float* __restrict__ Wo, const float* __restrict__ W1,
    const float* __restrict__ W2, const float* __restrict__ q,
    const float* __restrict__ qa, const float* __restrict__ pe,
    __bf16* __restrict__ ok, __bf16* __restrict__ ov,
    __bf16* __restrict__ oo, __bf16* __restrict__ o1,
    __bf16* __restrict__ o2, __bf16* __restrict__ xbf,
    __bf16* __restrict__ ybf)
{
    const int id = blockIdx.x, t = threadIdx.x;
    if (id < 1536) {
        const int z = id >> 8, r = id & 255;
        const int sel = z >> 1, i = z & 1;
        const float* src = sel == 0 ? Wk : (sel == 1 ? Wv : Wo);
        __bf16* dst = sel == 0 ? ok : (sel == 1 ? ov : oo);
        ttile(src + (long)i * 262144, dst + (long)i * 262144, 512, 512,
              r & 15, r >> 4, t);
    } else if (id < 3584) {
        int r = id - 1536; const int i = r >> 10; r &= 1023;
        ttile(W1 + (long)i * 1048576, o1 + (long)i * 1048576, 512, 2048,
              r & 63, r >> 6, t);
    } else if (id < 5632) {
        int r = id - 3584; const int i = r >> 10; r &= 1023;
        ttile(W2 + (long)i * 1048576, o2 + (long)i * 1048576, 2048, 512,
              r & 15, r >> 4, t);
    } else {
        const int n4 = B_ * S_ * D_ / 4;
        for (int i = (id - 5632) * 256 + t; i < n4; i += 2048 * 256) {
            float4 pv = ((const float4*)pe)[i & (S_ * D_ / 4 - 1)];
            float4 qv = ((const float4*)q)[i];
            float4 av = ((const float4*)qa)[i];
            bf16x4 xb = {(__bf16)(qv.x + pv.x), (__bf16)(qv.y + pv.y),
                         (__bf16)(qv.z + pv.z), (__bf16)(qv.w + pv.w)};
            ((bf16x4*)xbf)[i] = xb;
            bf16x4 yb = {(__bf16)(av.x + pv.x), (__bf16)(av.y + pv.y),
                         (__bf16)(av.z + pv.z), (__bf16)(av.w + pv.w)};
            ((bf16x4*)ybf)[i] = yb;
        }
    }
}

// ---- GEMM v5 (proven, frozen): 128x128, BK=64, T2 swizzle, T1 XCD swizzle ----
template <int RELU, int MODE>
__global__ __launch_bounds__(256) void gemm_kernel(
    const __bf16* __restrict__ A, const __bf16* __restrict__ Bt,
    const float* __restrict__ bias, const __bf16* __restrict__ res,
    __bf16* __restrict__ out, int M, int N, int K)
{
    __shared__ __bf16 As[2][128 * 64];
    __shared__ __bf16 Bs[2][128 * 64];
    const int t = threadIdx.x;
    const int lane = t & 63;
    const int wv = t >> 6, wr = wv >> 1, wc = wv & 1;
    const int lr = lane & 15, lk = lane >> 4;

    const int nwg = gridDim.x * gridDim.y;
    const int lin = blockIdx.y * gridDim.x + blockIdx.x;
    const int swz = (lin & 7) * (nwg >> 3) + (lin >> 3);
    const int m0 = (swz / gridDim.x) * 128, n0 = (swz % gridDim.x) * 128;

    const int srow = t >> 3;
    const int sslot = (t & 7) ^ (srow & 7);
    const __bf16* gA = A + (long)(m0 + srow) * K + sslot * 8;
    const __bf16* gB = Bt + (long)(n0 + srow) * K + sslot * 8;
    const long rstep = (long)32 * K;

    auto STAGE = [&](int bsel, int k0) {
        char* ldsA = (char*)As[bsel] + t * 16;
        char* ldsB = (char*)Bs[bsel] + t * 16;
        #pragma unroll
        for (int u = 0; u < 4; ++u) {
            gld_lds16(gA + u * rstep + k0, ldsA + u * 4096);
            gld_lds16(gB + u * rstep + k0, ldsB + u * 4096);
        }
    };

    f32x4 acc[4][4] = {};
    auto COMPUTE = [&](int bsel) {
        #pragma unroll
        for (int kk = 0; kk < 2; ++kk) {
            bf16x8 af[4], bfr[4];
            #pragma unroll
            for (int i = 0; i < 4; ++i) {
                const int rr = wr * 64 + i * 16 + lr;
                af[i] = *(const bf16x8*)((const char*)As[bsel] +
                        (rr << 7) + (((kk * 4 + lk) ^ (rr & 7)) << 4));
            }
            #pragma unroll
            for (int j = 0; j < 4; ++j) {
                const int rr = wc * 64 + j * 16 + lr;
                bfr[j] = *(const bf16x8*)((const char*)Bs[bsel] +
                         (rr << 7) + (((kk * 4 + lk) ^ (rr & 7)) << 4));
            }
            #pragma unroll
            for (int i = 0; i < 4; ++i)
                #pragma unroll
                for (int j = 0; j < 4; ++j)
                    acc[i][j] = __builtin_amdgcn_mfma_f32_16x16x32_bf16(
                        af[i], bfr[j], acc[i][j], 0, 0, 0);
        }
    };

    const int NT = K >> 6;
    STAGE(0, 0);
    STAGE(1, 64);
    for (int kt = 0; kt < NT - 1; ++kt) {
        asm volatile("s_waitcnt vmcnt(8)" ::: "memory");
        __builtin_amdgcn_s_barrier();
        COMPUTE(kt & 1);
        __builtin_amdgcn_s_barrier();
        if (kt + 2 < NT) STAGE(kt & 1, (kt + 2) << 6);
    }
    asm volatile("s_waitcnt vmcnt(0)" ::: "memory");
    __builtin_amdgcn_s_barrier();
    COMPUTE((NT - 1) & 1);

    #pragma unroll
    for (int i = 0; i < 4; ++i) {
        #pragma unroll
        for (int j = 0; j < 4; ++j) {
            const int n = n0 + wc * 64 + j * 16 + lr;
            const float bv = bias[n];
            #pragma unroll
            for (int r = 0; r < 4; ++r) {
                const int m = m0 + wr * 64 + i * 16 + lk * 4 + r;
                const long off = (long)m * N + n;
                float v = acc[i][j][r] + bv;
                if (MODE == 1) v += (float)res[off];
                if (RELU) v = v > 0.f ? v : 0.f;
                out[off] = (__bf16)v;
            }
        }
    }
}

// ---- GEMM8: 256x256, 8 waves, 8-phase interleave; R14: revert to the R10
// pipeline (vmcnt(8) twice per K-tile, 2-deep in-flight) which measured ~1 us
// faster than the R12 single-vmcnt(4) variant. Subtile reads proven
// conflict-free (8 lanes/bank-quad uniform = b128 minimum). ----
template <int RELU, int MODE>
__global__ __launch_bounds__(512, 2) void gemm8_kernel(
    const __bf16* __restrict__ A, const __bf16* __restrict__ Bt,
    const float* __restrict__ bias, const __bf16* __restrict__ res,
    __bf16* __restrict__ out, int M, int N, int K)
{
    __shared__ __bf16 lds[65536];  // 128 KB
    const int t = threadIdx.x;
    const int lane = t & 63, wv = t >> 6;
    const int wr = wv >> 2, wc = wv & 3;
    const int lr = lane & 15, lk = lane >> 4;

    const int nwg = gridDim.x * gridDim.y;
    const int lin = blockIdx.y * gridDim.x + blockIdx.x;
    const int swz = (lin & 7) * (nwg >> 3) + (lin >> 3);
    const int m0 = (swz / gridDim.x) * 256, n0 = (swz % gridDim.x) * 256;

    const int srcrow = lane >> 2;
    const int srccol = ((lane & 3) ^ ((lane >> 4) & 3)) * 8;
    auto STG = [&](int isB, int kt2, int kk2, int pb) {
        const __bf16* src = isB ? Bt : A;
        const int base = isB ? n0 : m0;
        #pragma unroll
        for (int u = 0; u < 2; ++u) {
            const int sr = u * 8 + wv;
            const long g = (long)(base + sr * 16 + srcrow) * K + kt2 * 64 + kk2 * 32 + srccol;
            char* d = (char*)lds + pb * 65536 + isB * 32768 + ((sr * 2 + kk2) << 10) + lane * 16;
            gld_lds16(src + g, d);
        }
    };

    f32x4 acc[8][4] = {};
    bf16x8 af[4], bfr[4];
    auto RDA = [&](int p, int kk, int mh) {
        #pragma unroll
        for (int i = 0; i < 4; ++i) {
            const int sr = wr * 8 + mh * 4 + i;
            af[i] = *(const bf16x8*)((const char*)lds + p * 65536 +
                    ((sr * 2 + kk) << 10) + lr * 64 + ((lk ^ ((lr >> 2) & 3)) << 4));
        }
    };
    auto RDB = [&](int p, int kk) {
        #pragma unroll
        for (int j = 0; j < 4; ++j) {
            const int sr = wc * 4 + j;
            bfr[j] = *(const bf16x8*)((const char*)lds + p * 65536 + 32768 +
                     ((sr * 2 + kk) << 10) + lr * 64 + ((lk ^ ((lr >> 2) & 3)) << 4));
        }
    };
    auto MM = [&](int mh) {
        __builtin_amdgcn_s_setprio(1);
        #pragma unroll
        for (int i = 0; i < 4; ++i)
            #pragma unroll
            for (int j = 0; j < 4; ++j)
                acc[mh * 4 + i][j] = __builtin_amdgcn_mfma_f32_16x16x32_bf16(
                    af[i], bfr[j], acc[mh * 4 + i][j], 0, 0, 0);
        __builtin_amdgcn_s_setprio(0);
    };

    const int NT = K >> 6;
    // prologue: t0 Ak0,Bk0,Ak1,Bk1; t1 Ak0,Bk0  (6 regions = 12 loads/thread)
    STG(0, 0, 0, 0); STG(1, 0, 0, 0); STG(0, 0, 1, 0); STG(1, 0, 1, 0);
    STG(0, 1, 0, 1); STG(1, 1, 0, 1);

    for (int kt = 0; kt < NT - 1; ++kt) {
        const int p = kt & 1;
        asm volatile("s_waitcnt vmcnt(8)" ::: "memory");   // tile kt k0 landed
        __builtin_amdgcn_s_barrier();
        RDA(p, 0, 0); RDB(p, 0); STG(0, kt + 1, 1, p ^ 1);
        MM(0);
        __builtin_amdgcn_s_barrier();
        RDA(p, 0, 1); STG(1, kt + 1, 1, p ^ 1);
        MM(1);
        asm volatile("s_waitcnt vmcnt(8)" ::: "memory");   // tile kt k1 landed
        __builtin_amdgcn_s_barrier();
        RDA(p, 1, 0); RDB(p, 1); if (kt + 2 < NT) STG(0, kt + 2, 0, p);
        MM(0);
        __builtin_amdgcn_s_barrier();
        RDA(p, 1, 1); if (kt + 2 < NT) STG(1, kt + 2, 0, p);
        MM(1);
    }
    {   // peeled last tile: no stages; drain exactly
        const int p = (NT - 1) & 1;
        asm volatile("s_waitcnt vmcnt(4)" ::: "memory");
        __builtin_amdgcn_s_barrier();
        RDA(p, 0, 0); RDB(p, 0); MM(0);
        __builtin_amdgcn_s_barrier();
        RDA(p, 0, 1); MM(1);
        asm volatile("s_waitcnt vmcnt(0)" ::: "memory");
        __builtin_amdgcn_s_barrier();
        RDA(p, 1, 0); RDB(p, 1); MM(0);
        __builtin_amdgcn_s_barrier();
        RDA(p, 1, 1); MM(1);
    }

    #pragma unroll
    for (int i = 0; i < 8; ++i) {
        #pragma unroll
        for (int j = 0; j < 4; ++j) {
            const int n = n0 + wc * 64 + j * 16 + lr;
            const float bv = bias[n];
            #pragma unroll
            for (int r = 0; r < 4; ++r) {
                const int m = m0 + wr * 128 + i * 16 + lk * 4 + r;
                const long off = (long)m * N + n;
                float v = acc[i][j][r] + bv;
                if (MODE == 1) v += (float)res[off];
                if (RELU) v = v > 0.f ? v : 0.f;
                out[off] = (__bf16)v;
            }
        }
    }
}

// ---- merged K+V projection (frozen) ----
__global__ __launch_bounds__(256) void gemm_kv(
    const __bf16* __restrict__ xbf, const __bf16* __restrict__ ybf,
    const __bf16* __restrict__ wkt, const __bf16* __restrict__ wvt,
    const float* __restrict__ bk, const float* __restrict__ bv,
    __bf16* __restrict__ kout, __bf16* __restrict__ vtout)
{
    constexpr int N = 512, K = 512;
    __shared__ __bf16 As[2][128 * 64];
    __shared__ __bf16 Bs[2][128 * 64];
    const int t = threadIdx.x;
    const int lane = t & 63;
    const int wv = t >> 6, wr = wv >> 1, wc = wv & 1;
    const int lr = lane & 15, lk = lane >> 4;
    const int zv = blockIdx.z;

    const __bf16* A  = zv ? ybf : xbf;
    const __bf16* Bt = zv ? wvt : wkt;
    const float* bias = zv ? bv : bk;
    __bf16* out = zv ? vtout : kout;

    const int nwg = gridDim.x * gridDim.y;
    const int lin = blockIdx.y * gridDim.x + blockIdx.x;
    const int swz = (lin & 7) * (nwg >> 3) + (lin >> 3);
    const int m0 = (swz / gridDim.x) * 128, n0 = (swz % gridDim.x) * 128;

    const int srow = t >> 3;
    const int sslot = (t & 7) ^ (srow & 7);
    const __bf16* gA = A + (long)(m0 + srow) * K + sslot * 8;
    const __bf16* gB = Bt + (long)(n0 + srow) * K + sslot * 8;
    const long rstep = (long)32 * K;

    auto STAGE = [&](int bsel, int k0) {
        char* ldsA = (char*)As[bsel] + t * 16;
        char* ldsB = (char*)Bs[bsel] + t * 16;
        #pragma unroll
        for (int u = 0; u < 4; ++u) {
            gld_lds16(gA + u * rstep + k0, ldsA + u * 4096);
            gld_lds16(gB + u * rstep + k0, ldsB + u * 4096);
        }
    };

    f32x4 acc[4][4] = {};
    auto COMPUTE = [&](int bsel) {
        #pragma unroll
        for (int kk = 0; kk < 2; ++kk) {
            bf16x8 af[4], bfr[4];
            #pragma unroll
            for (int i = 0; i < 4; ++i) {
                const int rr = wr * 64 + i * 16 + lr;
                af[i] = *(const bf16x8*)((const char*)As[bsel] +
                        (rr << 7) + (((kk * 4 + lk) ^ (rr & 7)) << 4));
            }
            #pragma unroll
            for (int j = 0; j < 4; ++j) {
                const int rr = wc * 64 + j * 16 + lr;
                bfr[j] = *(const bf16x8*)((const char*)Bs[bsel] +
                         (rr << 7) + (((kk * 4 + lk) ^ (rr & 7)) << 4));
            }
            #pragma unroll
            for (int i = 0; i < 4; ++i)
                #pragma unroll
                for (int j = 0; j < 4; ++j)
                    acc[i][j] = __builtin_amdgcn_mfma_f32_16x16x32_bf16(
                        af[i], bfr[j], acc[i][j], 0, 0, 0);
        }
    };

    const int NT = K >> 6;
    STAGE(0, 0);
    STAGE(1, 64);
    for (int kt = 0; kt < NT - 1; ++kt) {
        asm volatile("s_waitcnt vmcnt(8)" ::: "memory");
        __builtin_amdgcn_s_barrier();
        COMPUTE(kt & 1);
        __builtin_amdgcn_s_barrier();
        if (kt + 2 < NT) STAGE(kt & 1, (kt + 2) << 6);
    }
    asm volatile("s_waitcnt vmcnt(0)" ::: "memory");
    __builtin_amdgcn_s_barrier();
    COMPUTE((NT - 1) & 1);

    if (zv) {
        __syncthreads();
        __bf16* st = (__bf16*)As;
        #pragma unroll
        for (int i = 0; i < 4; ++i) {
            #pragma unroll
            for (int j = 0; j < 4; ++j) {
                const int nl = wc * 64 + j * 16 + lr;
                const float bvl = bias[n0 + nl];
                #pragma unroll
                for (int r = 0; r < 4; ++r) {
                    const int ml = wr * 64 + i * 16 + lk * 4 + r;
                    const int m16 = ml >> 3;
                    st[nl * 128 + (((m16 ^ (nl & 15)) << 3) | (ml & 7))] =
                        (__bf16)(acc[i][j][r] + bvl);
                }
            }
        }
        __syncthreads();
        const int rowh = t >> 2, c4 = t & 3;
        const int b = m0 >> 9;
        #pragma unroll
        for (int pass = 0; pass < 2; ++pass) {
            const int row = pass * 64 + rowh;
            const int n = n0 + row;
            __bf16* dst = out + (((long)((b * 8 + (n >> 6)) * 64 + (n & 63))) << 9)
                          + (m0 & 511);
            #pragma unroll
            for (int seg = 0; seg < 4; ++seg) {
                const int m16 = seg * 4 + c4;
                const bf16x8 vv =
                    *(const bf16x8*)&st[row * 128 + ((m16 ^ (row & 15)) << 3)];
                *(bf16x8*)(dst + m16 * 8) = vv;
            }
        }
    } else {
        #pragma unroll
        for (int i = 0; i < 4; ++i) {
            #pragma unroll
            for (int j = 0; j < 4; ++j) {
                const int n = n0 + wc * 64 + j * 16 + lr;
                const float bvl = bias[n];
                #pragma unroll
                for (int r = 0; r < 4; ++r) {
                    const int m = m0 + wr * 64 + i * 16 + lk * 4 + r;
                    out[(long)m * N + n] = (__bf16)(acc[i][j][r] + bvl);
                }
            }
        }
    }
}

// ---- attention v6 (proven) + R14: exp2 with log2e folded into frv ----
__global__ __launch_bounds__(512) void attn_kernel(
    const __bf16* __restrict__ Q, const __bf16* __restrict__ Vt,
    const float* __restrict__ fr, __bf16* __restrict__ Out)
{
    __shared__ __bf16 Ks[2][64 * 64];
    __shared__ __bf16 Vs[2][64 * 64];
    __shared__ __bf16 Plds[8][16 * 64];
    const int t = threadIdx.x;
    const int lane = t & 63, wv = t >> 6;          // wv 0..7
    const int lr = lane & 15, lk = lane >> 4;
    const int qb = blockIdx.x, h = blockIdx.y, b = blockIdx.z;
    const int qT = qb * 128 + wv * 16;

    const __bf16* qp = Q + (long)(b * S_ + qT + lr) * D_ + h * DK_ + lk * 8;
    const bf16x8 qf0 = *(const bf16x8*)qp;
    const bf16x8 qf1 = *(const bf16x8*)(qp + 32);

    float frv[4], ls[4];
    #pragma unroll
    for (int r = 0; r < 4; ++r) {
        // fold 1/sqrt(64) and log2(e): p = exp2(s * frv)
        frv[r] = fr[b * S_ + qT + lk * 4 + r] * (0.125f * 1.44269504088896f);
        ls[r] = 0.f;
    }
    f32x4 o[4] = {};

    const int srow = t >> 3;                        // 0..63 (full tile rows)
    const int sslot = (t & 7) ^ (srow & 7);         // XOR-swizzled 16B slot
    const __bf16* kstage = Q + (long)(b * S_ + srow) * D_ + h * DK_ + sslot * 8;
    const __bf16* vstage = Vt + ((long)(b * H_ + h) * DK_ + srow) * S_ + sslot * 8;
    __bf16* pl = &Plds[wv][0];
    const int sw = (lr & 7);

    auto STAGE = [&](int bsel, int ks) {            // 2 loads: whole K + whole V tile
        gld_lds16(kstage + (long)ks * D_, (char*)Ks[bsel] + t * 16);
        gld_lds16(vstage + ks, (char*)Vs[bsel] + t * 16);
    };

    auto COMPUTE = [&](int bsel, int ks) {
        if (ks >= qT + 16) return;                  // wave-uniform: fully masked
        f32x4 sc[4] = {};
        #pragma unroll
        for (int j = 0; j < 4; ++j) {
            const char* kb = (const char*)Ks[bsel] + ((j * 16 + lr) << 7);
            const bf16x8 kf0 = *(const bf16x8*)(kb + ((lk ^ sw) << 4));
            const bf16x8 kf1 = *(const bf16x8*)(kb + (((lk + 4) ^ sw) << 4));
            sc[j] = __builtin_amdgcn_mfma_f32_16x16x32_bf16(qf0, kf0, sc[j], 0, 0, 0);
            sc[j] = __builtin_amdgcn_mfma_f32_16x16x32_bf16(qf1, kf1, sc[j], 0, 0, 0);
        }
        #pragma unroll
        for (int j = 0; j < 4; ++j) {
            const int col = ks + j * 16 + lr;
            const int c8 = j * 2 + (lr >> 3), cb = lr & 7;
            #pragma unroll
            for (int r = 0; r < 4; ++r) {
                const int row = lk * 4 + r;
                const int sidx = row * 64 + ((c8 ^ (row & 7)) << 3) + cb;
                const float e = exp2f(sc[j][r] * frv[r]);
                const float p = (col < qT + row) ? e : 0.f;
                ls[r] += p;
                pl[sidx] = (__bf16)p;
            }
        }
        bf16x8 pf[2];
        #pragma unroll
        for (int kk = 0; kk < 2; ++kk) {
            const int ridx = lr * 64 + (((kk * 4 + lk) ^ sw) << 3);
            pf[kk] = *(const bf16x8*)&pl[ridx];
        }
        #pragma unroll
        for (int dt = 0; dt < 4; ++dt) {
            const char* vb = (const char*)Vs[bsel] + ((dt * 16 + lr) << 7);
            #pragma unroll
            for (int kk = 0; kk < 2; ++kk) {
                const bf16x8 vf = *(const bf16x8*)(vb + (((kk * 4 + lk) ^ sw) << 4));
                o[dt] = __builtin_amdgcn_mfma_f32_16x16x32_bf16(pf[kk], vf, o[dt], 0, 0, 0);
            }
        }
    };

    const int nt = 2 * qb + 2;                      // tiles covering 128 q-rows
    STAGE(0, 0);
    STAGE(1, 64);
    for (int tt = 0; tt < nt - 1; ++tt) {
        asm volatile("s_waitcnt vmcnt(2)" ::: "memory");
        __builtin_amdgcn_s_barrier();
        COMPUTE(tt & 1, tt * 64);
        __builtin_amdgcn_s_barrier();
        if (tt + 2 < nt) STAGE(tt & 1, (tt + 2) * 64);
    }
    asm volatile("s_waitcnt vmcnt(0)" ::: "memory");
    __builtin_amdgcn_s_barrier();
    COMPUTE((nt - 1) & 1, (nt - 1) * 64);

    #pragma unroll
    for (int r = 0; r < 4; ++r) {
        #pragma unroll
        for (int d = 1; d < 16; d <<= 1)
            ls[r] += __shfl_xor(ls[r], d);
        const float inv = ls[r] > 0.f ? 1.f / ls[r] : 0.f;  // row 0 -> zeros
        #pragma unroll
        for (int dt = 0; dt < 4; ++dt)
            Out[(long)(b * S_ + qT + lk * 4 + r) * D_ + h * DK_ + dt * 16 + lr] =
                (__bf16)(o[dt][r] * inv);
    }
}

// ---- LayerNorm: bf16 in; MODE 0: write bf16 xbf only; MODE 1: write fp32 only ----
__global__ __launch_bounds__(256) void ln_kernel(
    const __bf16* __restrict__ pre, const float* __restrict__ g,
    const float* __restrict__ be, float* __restrict__ xout,
    __bf16* __restrict__ xbf, int wf32)
{
    const int lane = threadIdx.x & 63, wv = threadIdx.x >> 6;
    const long row = (long)blockIdx.x * 4 + wv;
    const bf16x8 v = *(const bf16x8*)(pre + row * D_ + lane * 8);
    float f[8];
    #pragma unroll
    for (int k = 0; k < 8; ++k) f[k] = (float)v[k];
    float s = 0.f, ss = 0.f;
    #pragma unroll
    for (int k = 0; k < 8; ++k) { s += f[k]; ss += f[k] * f[k]; }
    #pragma unroll
    for (int d = 1; d < 64; d <<= 1) {
        s  += __shfl_xor(s, d);
        ss += __shfl_xor(ss, d);
    }
    const float mean = s * (1.f / 512.f);
    const float rstd = rsqrtf(ss * (1.f / 512.f) - mean * mean + 1e-5f);
    const float4 ga = ((const float4*)(g + lane * 8))[0];
    const float4 gc = ((const float4*)(g + lane * 8))[1];
    const float4 ba = ((const float4*)(be + lane * 8))[0];
    const float4 bc = ((const float4*)(be + lane * 8))[1];
    float o[8];
    o[0] = (f[0] - mean) * rstd * ga.x + ba.x;
    o[1] = (f[1] - mean) * rstd * ga.y + ba.y;
    o[2] = (f[2] - mean) * rstd * ga.z + ba.z;
    o[3] = (f[3] - mean) * rstd * ga.w + ba.w;
    o[4] = (f[4] - mean) * rstd * gc.x + bc.x;
    o[5] = (f[5] - mean) * rstd * gc.y + bc.y;
    o[6] = (f[6] - mean) * rstd * gc.z + bc.z;
    o[7] = (f[7] - mean) * rstd * gc.w + bc.w;
    if (wf32) {
        float* xo = xout + row * D_ + lane * 8;
        ((float4*)xo)[0] = make_float4(o[0], o[1], o[2], o[3]);
        ((float4*)xo)[1] = make_float4(o[4], o[5], o[6], o[7]);
    } else {
        bf16x8 xb = {(__bf16)o[0], (__bf16)o[1], (__bf16)o[2], (__bf16)o[3],
                     (__bf16)o[4], (__bf16)o[5], (__bf16)o[6], (__bf16)o[7]};
        *(bf16x8*)(xbf + row * D_ + lane * 8) = xb;
    }
}

extern "C" void kernel_launch(void* const* d_in, const int* in_sizes, int n_in,
                              void* d_out, int out_size, void* d_ws, size_t ws_size,
                              hipStream_t stream) {
    const float* q_embed = (const float*)d_in[0];
    const float* qa_embed = (const float*)d_in[1];
    const float* fr  = (const float*)d_in[2];
    const float* pe  = (const float*)d_in[3];
    const float* Wk  = (const float*)d_in[4];
    const float* bk  = (const float*)d_in[5];
    const float* Wv  = (const float*)d_in[6];
    const float* bv  = (const float*)d_in[7];
    const float* Wo  = (const float*)d_in[8];
    const float* bo  = (const float*)d_in[9];
    const float* g1  = (const float*)d_in[10];
    const float* be1 = (const float*)d_in[11];
    const float* W1  = (const float*)d_in[12];
    const float* bf1 = (const float*)d_in[13];
    const float* W2  = (const float*)d_in[14];
    const float* bf2 = (const float*)d_in[15];
    const float* g2  = (const float*)d_in[16];
    const float* be2 = (const float*)d_in[17];

    // workspace layout (~128 MB)
    char* ws = (char*)d_ws;
    __bf16* xbf   = (__bf16*)(ws + 0);           // 16 MB bf16 residual master
    __bf16* ybf   = (__bf16*)(ws + 16777216);    // 16 MB
    __bf16* pool  = (__bf16*)(ws + 33554432);    // 64 MB: k/vt/attn OR f1
    __bf16* preln = (__bf16*)(ws + 100663296);   // 16 MB
    __bf16* wts   = (__bf16*)(ws + 117440512);   // 11 MB bf16 transposed weights

    __bf16* kbuf  = pool;
    __bf16* vtbuf = pool + 8388608;
    __bf16* abuf  = pool + 2 * 8388608;
    __bf16* f1buf = pool;  // 64 MB, aliases k/vt/attn (all dead by FFN1)

    __bf16* wkt = wts;
    __bf16* wvt = wts + 524288;
    __bf16* wot = wts + 1048576;
    __bf16* w1t = wts + 1572864;
    __bf16* w2t = wts + 3670016;

    pre_all<<<7680, 256, 0, stream>>>(Wk, Wv, Wo, W1, W2, q_embed, qa_embed, pe,
                                      wkt, wvt, wot, w1t, w2t, xbf, ybf);

    for (int i = 0; i < 2; ++i) {
        gemm_kv<<<dim3(4, 128, 2), 256, 0, stream>>>(
            xbf, ybf, wkt + i * 262144, wvt + i * 262144,
            bk + i * 512, bv + i * 512, kbuf, vtbuf);
        attn_kernel<<<dim3(4, 8, 32), 512, 0, stream>>>(kbuf, vtbuf, fr, abuf);
        gemm_kernel<0, 1><<<dim3(4, 128), 256, 0, stream>>>(
            abuf, wot + i * 262144, bo + i * 512, xbf, preln, 16384, 512, 512);
        ln_kernel<<<4096, 256, 0, stream>>>(preln, g1 + i * 512, be1 + i * 512,
                                            (float*)d_out, xbf, 0);
        gemm8_kernel<1, 0><<<dim3(8, 64), 512, 0, stream>>>(
            xbf, w1t + i * 1048576, bf1 + i * 2048, nullptr, f1buf, 16384, 2048, 512);
        gemm_kernel<0, 1><<<dim3(4, 128), 256, 0, stream>>>(
            f1buf, w2t + i * 1048576, bf2 + i * 512, xbf, preln, 16384, 512, 2048);
        ln_kernel<<<4096, 256, 0, stream>>>(preln, g2 + i * 512, be2 + i * 512,
                                            (float*)d_out, xbf, i == 1 ? 1 : 0);
    }
}

// Round 15
// 406.474 us; speedup vs baseline: 1.0244x; 1.0244x over previous
//
#include <hip/hip_runtime.h>

#define B_ 32
#define S_ 512
#define D_ 512
#define H_ 8
#define DK_ 64
#define FF_ 2048

typedef float f32x4 __attribute__((ext_vector_type(4)));
typedef __bf16 bf16x8 __attribute__((ext_vector_type(8)));
typedef __bf16 bf16x4 __attribute__((ext_vector_type(4)));

// ---- async global->LDS, 16B per lane (dest must be wave-uniform base + lane*16) ----
__device__ __forceinline__ void gld_lds16(const void* gptr, void* lptr) {
    auto g = (__attribute__((address_space(1))) void*)(unsigned long long)gptr;
    auto l = (__attribute__((address_space(3))) void*)(unsigned)(unsigned long long)lptr;
    __builtin_amdgcn_global_load_lds(g, l, 16, 0, 0);
}

// ---- shared 32x32 transpose tile body: fp32 [R][C] -> bf16 [C][R] ----
__device__ __forceinline__ void ttile(
    const float* __restrict__ in, __bf16* __restrict__ out,
    int R, int C, int bx, int by, int t)
{
    __shared__ float tile[32][33];
    const int tc = bx * 32, tr = by * 32;
    const int lx = t & 31, ly = t >> 5;
    #pragma unroll
    for (int yy = ly; yy < 32; yy += 8)
        tile[yy][lx] = in[(long)(tr + yy) * C + tc + lx];
    __syncthreads();
    #pragma unroll
    for (int yy = ly; yy < 32; yy += 8)
        out[(long)(tc + yy) * R + tr + lx] = (__bf16)tile[lx][yy];
}

// ---- weight transposes + x/y prep fused into one flat-grid dispatch ----
__global__ __launch_bounds__(256) void pre_all(
    const float* __restrict__ Wk, const float* __restrict__ Wv,
    const float* __restrict__ Wo, const float* __restrict__ W1,
    const float* __restrict__ W2, const float* __restrict__ q,
    const float* __restrict__ qa, const float* __restrict__ pe,
    __bf16* __restrict__ ok, __bf16* __restrict__ ov,
    __bf16* __restrict__ oo, __bf16* __restrict__ o1,
    __bf16* __restrict__ o2, __bf16* __restrict__ xbf,
    __bf16* __restrict__ ybf)
{
    const int id = blockIdx.x, t = threadIdx.x;
    if (id < 1536) {
        const int z = id >> 8, r = id & 255;
        const int sel = z >> 1, i = z & 1;
        const float* src = sel == 0 ? Wk : (sel == 1 ? Wv : Wo);
        __bf16* dst = sel == 0 ? ok : (sel == 1 ? ov : oo);
        ttile(src + (long)i * 262144, dst + (long)i * 262144, 512, 512,
              r & 15, r >> 4, t);
    } else if (id < 3584) {
        int r = id - 1536; const int i = r >> 10; r &= 1023;
        ttile(W1 + (long)i * 1048576, o1 + (long)i * 1048576, 512, 2048,
              r & 63, r >> 6, t);
    } else if (id < 5632) {
        int r = id - 3584; const int i = r >> 10; r &= 1023;
        ttile(W2 + (long)i * 1048576, o2 + (long)i * 1048576, 2048, 512,
              r & 15, r >> 4, t);
    } else {
        const int n4 = B_ * S_ * D_ / 4;
        for (int i = (id - 5632) * 256 + t; i < n4; i += 2048 * 256) {
            float4 pv = ((const float4*)pe)[i & (S_ * D_ / 4 - 1)];
            float4 qv = ((const float4*)q)[i];
            float4 av = ((const float4*)qa)[i];
            bf16x4 xb = {(__bf16)(qv.x + pv.x), (__bf16)(qv.y + pv.y),
                         (__bf16)(qv.z + pv.z), (__bf16)(qv.w + pv.w)};
            ((bf16x4*)xbf)[i] = xb;
            bf16x4 yb = {(__bf16)(av.x + pv.x), (__bf16)(av.y + pv.y),
                         (__bf16)(av.z + pv.z), (__bf16)(av.w + pv.w)};
            ((bf16x4*)ybf)[i] = yb;
        }
    }
}

// ---- GEMM v5 (proven, frozen): 128x128, BK=64, T2 swizzle, T1 XCD swizzle ----
template <int RELU, int MODE>
__global__ __launch_bounds__(256) void gemm_kernel(
    const __bf16* __restrict__ A, const __bf16* __restrict__ Bt,
    const float* __restrict__ bias, const __bf16* __restrict__ res,
    __bf16* __restrict__ out, int M, int N, int K)
{
    __shared__ __bf16 As[2][128 * 64];
    __shared__ __bf16 Bs[2][128 * 64];
    const int t = threadIdx.x;
    const int lane = t & 63;
    const int wv = t >> 6, wr = wv >> 1, wc = wv & 1;
    const int lr = lane & 15, lk = lane >> 4;

    const int nwg = gridDim.x * gridDim.y;
    const int lin = blockIdx.y * gridDim.x + blockIdx.x;
    const int swz = (lin & 7) * (nwg >> 3) + (lin >> 3);
    const int m0 = (swz / gridDim.x) * 128, n0 = (swz % gridDim.x) * 128;

    const int srow = t >> 3;
    const int sslot = (t & 7) ^ (srow & 7);
    const __bf16* gA = A + (long)(m0 + srow) * K + sslot * 8;
    const __bf16* gB = Bt + (long)(n0 + srow) * K + sslot * 8;
    const long rstep = (long)32 * K;

    auto STAGE = [&](int bsel, int k0) {
        char* ldsA = (char*)As[bsel] + t * 16;
        char* ldsB = (char*)Bs[bsel] + t * 16;
        #pragma unroll
        for (int u = 0; u < 4; ++u) {
            gld_lds16(gA + u * rstep + k0, ldsA + u * 4096);
            gld_lds16(gB + u * rstep + k0, ldsB + u * 4096);
        }
    };

    f32x4 acc[4][4] = {};
    auto COMPUTE = [&](int bsel) {
        #pragma unroll
        for (int kk = 0; kk < 2; ++kk) {
            bf16x8 af[4], bfr[4];
            #pragma unroll
            for (int i = 0; i < 4; ++i) {
                const int rr = wr * 64 + i * 16 + lr;
                af[i] = *(const bf16x8*)((const char*)As[bsel] +
                        (rr << 7) + (((kk * 4 + lk) ^ (rr & 7)) << 4));
            }
            #pragma unroll
            for (int j = 0; j < 4; ++j) {
                const int rr = wc * 64 + j * 16 + lr;
                bfr[j] = *(const bf16x8*)((const char*)Bs[bsel] +
                         (rr << 7) + (((kk * 4 + lk) ^ (rr & 7)) << 4));
            }
            #pragma unroll
            for (int i = 0; i < 4; ++i)
                #pragma unroll
                for (int j = 0; j < 4; ++j)
                    acc[i][j] = __builtin_amdgcn_mfma_f32_16x16x32_bf16(
                        af[i], bfr[j], acc[i][j], 0, 0, 0);
        }
    };

    const int NT = K >> 6;
    STAGE(0, 0);
    STAGE(1, 64);
    for (int kt = 0; kt < NT - 1; ++kt) {
        asm volatile("s_waitcnt vmcnt(8)" ::: "memory");
        __builtin_amdgcn_s_barrier();
        COMPUTE(kt & 1);
        __builtin_amdgcn_s_barrier();
        if (kt + 2 < NT) STAGE(kt & 1, (kt + 2) << 6);
    }
    asm volatile("s_waitcnt vmcnt(0)" ::: "memory");
    __builtin_amdgcn_s_barrier();
    COMPUTE((NT - 1) & 1);

    #pragma unroll
    for (int i = 0; i < 4; ++i) {
        #pragma unroll
        for (int j = 0; j < 4; ++j) {
            const int n = n0 + wc * 64 + j * 16 + lr;
            const float bv = bias[n];
            #pragma unroll
            for (int r = 0; r < 4; ++r) {
                const int m = m0 + wr * 64 + i * 16 + lk * 4 + r;
                const long off = (long)m * N + n;
                float v = acc[i][j][r] + bv;
                if (MODE == 1) v += (float)res[off];
                if (RELU) v = v > 0.f ? v : 0.f;
                out[off] = (__bf16)v;
            }
        }
    }
}

// ---- GEMM8 (R10 pipeline, kept): 256x256, 8 waves, 8-phase interleave ----
template <int RELU, int MODE>
__global__ __launch_bounds__(512, 2) void gemm8_kernel(
    const __bf16* __restrict__ A, const __bf16* __restrict__ Bt,
    const float* __restrict__ bias, const __bf16* __restrict__ res,
    __bf16* __restrict__ out, int M, int N, int K)
{
    __shared__ __bf16 lds[65536];  // 128 KB
    const int t = threadIdx.x;
    const int lane = t & 63, wv = t >> 6;
    const int wr = wv >> 2, wc = wv & 3;
    const int lr = lane & 15, lk = lane >> 4;

    const int nwg = gridDim.x * gridDim.y;
    const int lin = blockIdx.y * gridDim.x + blockIdx.x;
    const int swz = (lin & 7) * (nwg >> 3) + (lin >> 3);
    const int m0 = (swz / gridDim.x) * 256, n0 = (swz % gridDim.x) * 256;

    const int srcrow = lane >> 2;
    const int srccol = ((lane & 3) ^ ((lane >> 4) & 3)) * 8;
    auto STG = [&](int isB, int kt2, int kk2, int pb) {
        const __bf16* src = isB ? Bt : A;
        const int base = isB ? n0 : m0;
        #pragma unroll
        for (int u = 0; u < 2; ++u) {
            const int sr = u * 8 + wv;
            const long g = (long)(base + sr * 16 + srcrow) * K + kt2 * 64 + kk2 * 32 + srccol;
            char* d = (char*)lds + pb * 65536 + isB * 32768 + ((sr * 2 + kk2) << 10) + lane * 16;
            gld_lds16(src + g, d);
        }
    };

    f32x4 acc[8][4] = {};
    bf16x8 af[4], bfr[4];
    auto RDA = [&](int p, int kk, int mh) {
        #pragma unroll
        for (int i = 0; i < 4; ++i) {
            const int sr = wr * 8 + mh * 4 + i;
            af[i] = *(const bf16x8*)((const char*)lds + p * 65536 +
                    ((sr * 2 + kk) << 10) + lr * 64 + ((lk ^ ((lr >> 2) & 3)) << 4));
        }
    };
    auto RDB = [&](int p, int kk) {
        #pragma unroll
        for (int j = 0; j < 4; ++j) {
            const int sr = wc * 4 + j;
            bfr[j] = *(const bf16x8*)((const char*)lds + p * 65536 + 32768 +
                     ((sr * 2 + kk) << 10) + lr * 64 + ((lk ^ ((lr >> 2) & 3)) << 4));
        }
    };
    auto MM = [&](int mh) {
        __builtin_amdgcn_s_setprio(1);
        #pragma unroll
        for (int i = 0; i < 4; ++i)
            #pragma unroll
            for (int j = 0; j < 4; ++j)
                acc[mh * 4 + i][j] = __builtin_amdgcn_mfma_f32_16x16x32_bf16(
                    af[i], bfr[j], acc[mh * 4 + i][j], 0, 0, 0);
        __builtin_amdgcn_s_setprio(0);
    };

    const int NT = K >> 6;
    STG(0, 0, 0, 0); STG(1, 0, 0, 0); STG(0, 0, 1, 0); STG(1, 0, 1, 0);
    STG(0, 1, 0, 1); STG(1, 1, 0, 1);

    for (int kt = 0; kt < NT - 1; ++kt) {
        const int p = kt & 1;
        asm volatile("s_waitcnt vmcnt(8)" ::: "memory");
        __builtin_amdgcn_s_barrier();
        RDA(p, 0, 0); RDB(p, 0); STG(0, kt + 1, 1, p ^ 1);
        MM(0);
        __builtin_amdgcn_s_barrier();
        RDA(p, 0, 1); STG(1, kt + 1, 1, p ^ 1);
        MM(1);
        asm volatile("s_waitcnt vmcnt(8)" ::: "memory");
        __builtin_amdgcn_s_barrier();
        RDA(p, 1, 0); RDB(p, 1); if (kt + 2 < NT) STG(0, kt + 2, 0, p);
        MM(0);
        __builtin_amdgcn_s_barrier();
        RDA(p, 1, 1); if (kt + 2 < NT) STG(1, kt + 2, 0, p);
        MM(1);
    }
    {
        const int p = (NT - 1) & 1;
        asm volatile("s_waitcnt vmcnt(4)" ::: "memory");
        __builtin_amdgcn_s_barrier();
        RDA(p, 0, 0); RDB(p, 0); MM(0);
        __builtin_amdgcn_s_barrier();
        RDA(p, 0, 1); MM(1);
        asm volatile("s_waitcnt vmcnt(0)" ::: "memory");
        __builtin_amdgcn_s_barrier();
        RDA(p, 1, 0); RDB(p, 1); MM(0);
        __builtin_amdgcn_s_barrier();
        RDA(p, 1, 1); MM(1);
    }

    #pragma unroll
    for (int i = 0; i < 8; ++i) {
        #pragma unroll
        for (int j = 0; j < 4; ++j) {
            const int n = n0 + wc * 64 + j * 16 + lr;
            const float bv = bias[n];
            #pragma unroll
            for (int r = 0; r < 4; ++r) {
                const int m = m0 + wr * 128 + i * 16 + lk * 4 + r;
                const long off = (long)m * N + n;
                float v = acc[i][j][r] + bv;
                if (MODE == 1) v += (float)res[off];
                if (RELU) v = v > 0.f ? v : 0.f;
                out[off] = (__bf16)v;
            }
        }
    }
}

// ---- merged K+V projection (frozen) ----
__global__ __launch_bounds__(256) void gemm_kv(
    const __bf16* __restrict__ xbf, const __bf16* __restrict__ ybf,
    const __bf16* __restrict__ wkt, const __bf16* __restrict__ wvt,
    const float* __restrict__ bk, const float* __restrict__ bv,
    __bf16* __restrict__ kout, __bf16* __restrict__ vtout)
{
    constexpr int N = 512, K = 512;
    __shared__ __bf16 As[2][128 * 64];
    __shared__ __bf16 Bs[2][128 * 64];
    const int t = threadIdx.x;
    const int lane = t & 63;
    const int wv = t >> 6, wr = wv >> 1, wc = wv & 1;
    const int lr = lane & 15, lk = lane >> 4;
    const int zv = blockIdx.z;

    const __bf16* A  = zv ? ybf : xbf;
    const __bf16* Bt = zv ? wvt : wkt;
    const float* bias = zv ? bv : bk;
    __bf16* out = zv ? vtout : kout;

    const int nwg = gridDim.x * gridDim.y;
    const int lin = blockIdx.y * gridDim.x + blockIdx.x;
    const int swz = (lin & 7) * (nwg >> 3) + (lin >> 3);
    const int m0 = (swz / gridDim.x) * 128, n0 = (swz % gridDim.x) * 128;

    const int srow = t >> 3;
    const int sslot = (t & 7) ^ (srow & 7);
    const __bf16* gA = A + (long)(m0 + srow) * K + sslot * 8;
    const __bf16* gB = Bt + (long)(n0 + srow) * K + sslot * 8;
    const long rstep = (long)32 * K;

    auto STAGE = [&](int bsel, int k0) {
        char* ldsA = (char*)As[bsel] + t * 16;
        char* ldsB = (char*)Bs[bsel] + t * 16;
        #pragma unroll
        for (int u = 0; u < 4; ++u) {
            gld_lds16(gA + u * rstep + k0, ldsA + u * 4096);
            gld_lds16(gB + u * rstep + k0, ldsB + u * 4096);
        }
    };

    f32x4 acc[4][4] = {};
    auto COMPUTE = [&](int bsel) {
        #pragma unroll
        for (int kk = 0; kk < 2; ++kk) {
            bf16x8 af[4], bfr[4];
            #pragma unroll
            for (int i = 0; i < 4; ++i) {
                const int rr = wr * 64 + i * 16 + lr;
                af[i] = *(const bf16x8*)((const char*)As[bsel] +
                        (rr << 7) + (((kk * 4 + lk) ^ (rr & 7)) << 4));
            }
            #pragma unroll
            for (int j = 0; j < 4; ++j) {
                const int rr = wc * 64 + j * 16 + lr;
                bfr[j] = *(const bf16x8*)((const char*)Bs[bsel] +
                         (rr << 7) + (((kk * 4 + lk) ^ (rr & 7)) << 4));
            }
            #pragma unroll
            for (int i = 0; i < 4; ++i)
                #pragma unroll
                for (int j = 0; j < 4; ++j)
                    acc[i][j] = __builtin_amdgcn_mfma_f32_16x16x32_bf16(
                        af[i], bfr[j], acc[i][j], 0, 0, 0);
        }
    };

    const int NT = K >> 6;
    STAGE(0, 0);
    STAGE(1, 64);
    for (int kt = 0; kt < NT - 1; ++kt) {
        asm volatile("s_waitcnt vmcnt(8)" ::: "memory");
        __builtin_amdgcn_s_barrier();
        COMPUTE(kt & 1);
        __builtin_amdgcn_s_barrier();
        if (kt + 2 < NT) STAGE(kt & 1, (kt + 2) << 6);
    }
    asm volatile("s_waitcnt vmcnt(0)" ::: "memory");
    __builtin_amdgcn_s_barrier();
    COMPUTE((NT - 1) & 1);

    if (zv) {
        __syncthreads();
        __bf16* st = (__bf16*)As;
        #pragma unroll
        for (int i = 0; i < 4; ++i) {
            #pragma unroll
            for (int j = 0; j < 4; ++j) {
                const int nl = wc * 64 + j * 16 + lr;
                const float bvl = bias[n0 + nl];
                #pragma unroll
                for (int r = 0; r < 4; ++r) {
                    const int ml = wr * 64 + i * 16 + lk * 4 + r;
                    const int m16 = ml >> 3;
                    st[nl * 128 + (((m16 ^ (nl & 15)) << 3) | (ml & 7))] =
                        (__bf16)(acc[i][j][r] + bvl);
                }
            }
        }
        __syncthreads();
        const int rowh = t >> 2, c4 = t & 3;
        const int b = m0 >> 9;
        #pragma unroll
        for (int pass = 0; pass < 2; ++pass) {
            const int row = pass * 64 + rowh;
            const int n = n0 + row;
            __bf16* dst = out + (((long)((b * 8 + (n >> 6)) * 64 + (n & 63))) << 9)
                          + (m0 & 511);
            #pragma unroll
            for (int seg = 0; seg < 4; ++seg) {
                const int m16 = seg * 4 + c4;
                const bf16x8 vv =
                    *(const bf16x8*)&st[row * 128 + ((m16 ^ (row & 15)) << 3)];
                *(bf16x8*)(dst + m16 * 8) = vv;
            }
        }
    } else {
        #pragma unroll
        for (int i = 0; i < 4; ++i) {
            #pragma unroll
            for (int j = 0; j < 4; ++j) {
                const int n = n0 + wc * 64 + j * 16 + lr;
                const float bvl = bias[n];
                #pragma unroll
                for (int r = 0; r < 4; ++r) {
                    const int m = m0 + wr * 64 + i * 16 + lk * 4 + r;
                    out[(long)m * N + n] = (__bf16)(acc[i][j][r] + bvl);
                }
            }
        }
    }
}

// ---- attention v6 (proven R13 form): 8-wave / 128-row blocks, __expf ----
__global__ __launch_bounds__(512) void attn_kernel(
    const __bf16* __restrict__ Q, const __bf16* __restrict__ Vt,
    const float* __restrict__ fr, __bf16* __restrict__ Out)
{
    __shared__ __bf16 Ks[2][64 * 64];
    __shared__ __bf16 Vs[2][64 * 64];
    __shared__ __bf16 Plds[8][16 * 64];
    const int t = threadIdx.x;
    const int lane = t & 63, wv = t >> 6;          // wv 0..7
    const int lr = lane & 15, lk = lane >> 4;
    const int qb = blockIdx.x, h = blockIdx.y, b = blockIdx.z;
    const int qT = qb * 128 + wv * 16;

    const __bf16* qp = Q + (long)(b * S_ + qT + lr) * D_ + h * DK_ + lk * 8;
    const bf16x8 qf0 = *(const bf16x8*)qp;
    const bf16x8 qf1 = *(const bf16x8*)(qp + 32);

    float frv[4], ls[4];
    #pragma unroll
    for (int r = 0; r < 4; ++r) {
        frv[r] = fr[b * S_ + qT + lk * 4 + r] * 0.125f;  // fold 1/sqrt(64)
        ls[r] = 0.f;
    }
    f32x4 o[4] = {};

    const int srow = t >> 3;                        // 0..63 (full tile rows)
    const int sslot = (t & 7) ^ (srow & 7);         // XOR-swizzled 16B slot
    const __bf16* kstage = Q + (long)(b * S_ + srow) * D_ + h * DK_ + sslot * 8;
    const __bf16* vstage = Vt + ((long)(b * H_ + h) * DK_ + srow) * S_ + sslot * 8;
    __bf16* pl = &Plds[wv][0];
    const int sw = (lr & 7);

    auto STAGE = [&](int bsel, int ks) {            // 2 loads: whole K + whole V tile
        gld_lds16(kstage + (long)ks * D_, (char*)Ks[bsel] + t * 16);
        gld_lds16(vstage + ks, (char*)Vs[bsel] + t * 16);
    };

    auto COMPUTE = [&](int bsel, int ks) {
        if (ks >= qT + 16) return;                  // wave-uniform: fully masked
        f32x4 sc[4] = {};
        #pragma unroll
        for (int j = 0; j < 4; ++j) {
            const char* kb = (const char*)Ks[bsel] + ((j * 16 + lr) << 7);
            const bf16x8 kf0 = *(const bf16x8*)(kb + ((lk ^ sw) << 4));
            const bf16x8 kf1 = *(const bf16x8*)(kb + (((lk + 4) ^ sw) << 4));
            sc[j] = __builtin_amdgcn_mfma_f32_16x16x32_bf16(qf0, kf0, sc[j], 0, 0, 0);
            sc[j] = __builtin_amdgcn_mfma_f32_16x16x32_bf16(qf1, kf1, sc[j], 0, 0, 0);
        }
        #pragma unroll
        for (int j = 0; j < 4; ++j) {
            const int col = ks + j * 16 + lr;
            const int c8 = j * 2 + (lr >> 3), cb = lr & 7;
            #pragma unroll
            for (int r = 0; r < 4; ++r) {
                const int row = lk * 4 + r;
                const int sidx = row * 64 + ((c8 ^ (row & 7)) << 3) + cb;
                const float e = __expf(sc[j][r] * frv[r]);
                const float p = (col < qT + row) ? e : 0.f;
                ls[r] += p;
                pl[sidx] = (__bf16)p;
            }
        }
        bf16x8 pf[2];
        #pragma unroll
        for (int kk = 0; kk < 2; ++kk) {
            const int ridx = lr * 64 + (((kk * 4 + lk) ^ sw) << 3);
            pf[kk] = *(const bf16x8*)&pl[ridx];
        }
        #pragma unroll
        for (int dt = 0; dt < 4; ++dt) {
            const char* vb = (const char*)Vs[bsel] + ((dt * 16 + lr) << 7);
            #pragma unroll
            for (int kk = 0; kk < 2; ++kk) {
                const bf16x8 vf = *(const bf16x8*)(vb + (((kk * 4 + lk) ^ sw) << 4));
                o[dt] = __builtin_amdgcn_mfma_f32_16x16x32_bf16(pf[kk], vf, o[dt], 0, 0, 0);
            }
        }
    };

    const int nt = 2 * qb + 2;                      // tiles covering 128 q-rows
    STAGE(0, 0);
    STAGE(1, 64);
    for (int tt = 0; tt < nt - 1; ++tt) {
        asm volatile("s_waitcnt vmcnt(2)" ::: "memory");
        __builtin_amdgcn_s_barrier();
        COMPUTE(tt & 1, tt * 64);
        __builtin_amdgcn_s_barrier();
        if (tt + 2 < nt) STAGE(tt & 1, (tt + 2) * 64);
    }
    asm volatile("s_waitcnt vmcnt(0)" ::: "memory");
    __builtin_amdgcn_s_barrier();
    COMPUTE((nt - 1) & 1, (nt - 1) * 64);

    #pragma unroll
    for (int r = 0; r < 4; ++r) {
        #pragma unroll
        for (int d = 1; d < 16; d <<= 1)
            ls[r] += __shfl_xor(ls[r], d);
        const float inv = ls[r] > 0.f ? 1.f / ls[r] : 0.f;  // row 0 -> zeros
        #pragma unroll
        for (int dt = 0; dt < 4; ++dt)
            Out[(long)(b * S_ + qT + lk * 4 + r) * D_ + h * DK_ + dt * 16 + lr] =
                (__bf16)(o[dt][r] * inv);
    }
}

// ---- LayerNorm: bf16 in; wf32=0: write bf16 xbf only; wf32=1: write fp32 only ----
__global__ __launch_bounds__(256) void ln_kernel(
    const __bf16* __restrict__ pre, const float* __restrict__ g,
    const float* __restrict__ be, float* __restrict__ xout,
    __bf16* __restrict__ xbf, int wf32)
{
    const int lane = threadIdx.x & 63, wv = threadIdx.x >> 6;
    const long row = (long)blockIdx.x * 4 + wv;
    const bf16x8 v = *(const bf16x8*)(pre + row * D_ + lane * 8);
    float f[8];
    #pragma unroll
    for (int k = 0; k < 8; ++k) f[k] = (float)v[k];
    float s = 0.f, ss = 0.f;
    #pragma unroll
    for (int k = 0; k < 8; ++k) { s += f[k]; ss += f[k] * f[k]; }
    #pragma unroll
    for (int d = 1; d < 64; d <<= 1) {
        s  += __shfl_xor(s, d);
        ss += __shfl_xor(ss, d);
    }
    const float mean = s * (1.f / 512.f);
    const float rstd = rsqrtf(ss * (1.f / 512.f) - mean * mean + 1e-5f);
    const float4 ga = ((const float4*)(g + lane * 8))[0];
    const float4 gc = ((const float4*)(g + lane * 8))[1];
    const float4 ba = ((const float4*)(be + lane * 8))[0];
    const float4 bc = ((const float4*)(be + lane * 8))[1];
    float o[8];
    o[0] = (f[0] - mean) * rstd * ga.x + ba.x;
    o[1] = (f[1] - mean) * rstd * ga.y + ba.y;
    o[2] = (f[2] - mean) * rstd * ga.z + ba.z;
    o[3] = (f[3] - mean) * rstd * ga.w + ba.w;
    o[4] = (f[4] - mean) * rstd * gc.x + bc.x;
    o[5] = (f[5] - mean) * rstd * gc.y + bc.y;
    o[6] = (f[6] - mean) * rstd * gc.z + bc.z;
    o[7] = (f[7] - mean) * rstd * gc.w + bc.w;
    if (wf32) {
        float* xo = xout + row * D_ + lane * 8;
        ((float4*)xo)[0] = make_float4(o[0], o[1], o[2], o[3]);
        ((float4*)xo)[1] = make_float4(o[4], o[5], o[6], o[7]);
    } else {
        bf16x8 xb = {(__bf16)o[0], (__bf16)o[1], (__bf16)o[2], (__bf16)o[3],
                     (__bf16)o[4], (__bf16)o[5], (__bf16)o[6], (__bf16)o[7]};
        *(bf16x8*)(xbf + row * D_ + lane * 8) = xb;
    }
}

extern "C" void kernel_launch(void* const* d_in, const int* in_sizes, int n_in,
                              void* d_out, int out_size, void* d_ws, size_t ws_size,
                              hipStream_t stream) {
    const float* q_embed = (const float*)d_in[0];
    const float* qa_embed = (const float*)d_in[1];
    const float* fr  = (const float*)d_in[2];
    const float* pe  = (const float*)d_in[3];
    const float* Wk  = (const float*)d_in[4];
    const float* bk  = (const float*)d_in[5];
    const float* Wv  = (const float*)d_in[6];
    const float* bv  = (const float*)d_in[7];
    const float* Wo  = (const float*)d_in[8];
    const float* bo  = (const float*)d_in[9];
    const float* g1  = (const float*)d_in[10];
    const float* be1 = (const float*)d_in[11];
    const float* W1  = (const float*)d_in[12];
    const float* bf1 = (const float*)d_in[13];
    const float* W2  = (const float*)d_in[14];
    const float* bf2 = (const float*)d_in[15];
    const float* g2  = (const float*)d_in[16];
    const float* be2 = (const float*)d_in[17];

    // workspace layout (~128 MB)
    char* ws = (char*)d_ws;
    __bf16* xbf   = (__bf16*)(ws + 0);           // 16 MB bf16 residual master
    __bf16* ybf   = (__bf16*)(ws + 16777216);    // 16 MB
    __bf16* pool  = (__bf16*)(ws + 33554432);    // 64 MB: k/vt/attn OR f1
    __bf16* preln = (__bf16*)(ws + 100663296);   // 16 MB
    __bf16* wts   = (__bf16*)(ws + 117440512);   // 11 MB bf16 transposed weights

    __bf16* kbuf  = pool;
    __bf16* vtbuf = pool + 8388608;
    __bf16* abuf  = pool + 2 * 8388608;
    __bf16* f1buf = pool;  // 64 MB, aliases k/vt/attn (all dead by FFN1)

    __bf16* wkt = wts;
    __bf16* wvt = wts + 524288;
    __bf16* wot = wts + 1048576;
    __bf16* w1t = wts + 1572864;
    __bf16* w2t = wts + 3670016;

    pre_all<<<7680, 256, 0, stream>>>(Wk, Wv, Wo, W1, W2, q_embed, qa_embed, pe,
                                      wkt, wvt, wot, w1t, w2t, xbf, ybf);

    for (int i = 0; i < 2; ++i) {
        gemm_kv<<<dim3(4, 128, 2), 256, 0, stream>>>(
            xbf, ybf, wkt + i * 262144, wvt + i * 262144,
            bk + i * 512, bv + i * 512, kbuf, vtbuf);
        attn_kernel<<<dim3(4, 8, 32), 512, 0, stream>>>(kbuf, vtbuf, fr, abuf);
        gemm_kernel<0, 1><<<dim3(4, 128), 256, 0, stream>>>(
            abuf, wot + i * 262144, bo + i * 512, xbf, preln, 16384, 512, 512);
        ln_kernel<<<4096, 256, 0, stream>>>(preln, g1 + i * 512, be1 + i * 512,
                                            (float*)d_out, xbf, 0);
        gemm8_kernel<1, 0><<<dim3(8, 64), 512, 0, stream>>>(
            xbf, w1t + i * 1048576, bf1 + i * 2048, nullptr, f1buf, 16384, 2048, 512);
        gemm_kernel<0, 1><<<dim3(4, 128), 256, 0, stream>>>(
            f1buf, w2t + i * 1048576, bf2 + i * 512, xbf, preln, 16384, 512, 2048);
        ln_kernel<<<4096, 256, 0, stream>>>(preln, g2 + i * 512, be2 + i * 512,
                                            (float*)d_out, xbf, i == 1 ? 1 : 0);
    }
}